// Round 1
// baseline (171.856 us; speedup 1.0000x reference)
//
#include <hip/hip_runtime.h>

#define D_DIM 640
#define M_DIM 1024
#define B_DIM 32
#define BK 32
#define OUT_ROW 205120  // 640*641/2

typedef __bf16 bf16x8 __attribute__((ext_vector_type(8)));
typedef float f32x4 __attribute__((ext_vector_type(4)));

__device__ __forceinline__ unsigned short f2bf(float f) {
    union { float f; unsigned int u; } c; c.f = f;
    unsigned int u = c.u;
    unsigned int r = (u + 0x7fffu + ((u >> 16) & 1u)) >> 16;
    return (unsigned short)r;
}

__device__ __forceinline__ float bf2f(unsigned short h) {
    union { unsigned int u; float f; } c; c.u = ((unsigned int)h) << 16;
    return c.f;
}

__device__ __forceinline__ void gload_lds16(const unsigned short* g, unsigned short* l) {
    __builtin_amdgcn_global_load_lds(
        (const __attribute__((address_space(1))) unsigned int*)g,
        (__attribute__((address_space(3))) unsigned int*)l,
        16, 0, 0);
}

__device__ __forceinline__ float block_reduce_256(float s) {
    #pragma unroll
    for (int off = 32; off > 0; off >>= 1) s += __shfl_down(s, off, 64);
    __shared__ float red[4];
    if ((threadIdx.x & 63) == 0) red[threadIdx.x >> 6] = s;
    __syncthreads();
    return red[0] + red[1] + red[2] + red[3];
}

__device__ __forceinline__ float block_reduce_512(float s) {
    #pragma unroll
    for (int off = 32; off > 0; off >>= 1) s += __shfl_down(s, off, 64);
    __shared__ float red[8];
    if ((threadIdx.x & 63) == 0) red[threadIdx.x >> 6] = s;
    __syncthreads();
    float t = 0.f;
    #pragma unroll
    for (int i = 0; i < 8; i++) t += red[i];
    return t;
}

// Kernel 1: fp32 -> bf16 cast + per-row sum of squares; zeroes accumulators.
__global__ void cast_diag_kernel(const float* __restrict__ x,
                                 unsigned short* __restrict__ xb,
                                 float* __restrict__ diag,
                                 float* __restrict__ rowsum,
                                 float* __restrict__ tot) {
    const size_t row = blockIdx.x;
    const int t = threadIdx.x;
    const float4 v = ((const float4*)(x + row * M_DIM))[t];
    float s = v.x * v.x + v.y * v.y + v.z * v.z + v.w * v.w;
    ushort4 o;
    o.x = f2bf(v.x); o.y = f2bf(v.y); o.z = f2bf(v.z); o.w = f2bf(v.w);
    ((ushort4*)(xb + row * M_DIM))[t] = o;
    float ssum = block_reduce_256(s);
    if (t == 0) { diag[row] = ssum; rowsum[row] = 0.f; }
    if (t == 1 && row < B_DIM) tot[row] = 0.f;
}

// Kernel 2: symmetric batched G = X X^T, upper-tri tiles (it<=jt), fused
// dcov epilogue (bf16 store) + rowsum/tot atomics.
// CHANGE vs prev: 512 threads (8 waves, 2x4 wave grid, 64x32 per wave).
// Same 128x128 tile, same 4-phase 64KB pipeline, same XOR-swizzle pair.
// Occupancy: LDS still caps at 2 blocks/CU, but waves/CU 7.5 -> 15 — the
// counters showed a latency-bound loop (MfmaUtil 9.7%, HBM 8%, occ 18.5%),
// so double the resident waves to hide the per-barrier memory latency.
// Staging: 512 thr x 16B = full 128x32 tile per gload call -> 2 loads/thr/iter.
__global__ __launch_bounds__(512, 4)
void gemm_dcov_kernel(const unsigned short* __restrict__ xb,
                      const float* __restrict__ diag,
                      unsigned short* __restrict__ dcov,
                      float* __restrict__ rowsum,
                      float* __restrict__ tot) {
    // 4 phases x (A 4096 + B 4096 shorts) = 32768 shorts = 64 KB
    __shared__ __align__(16) unsigned short smem[32768];

    const int id = blockIdx.x;
    const int bt = (id & 7) * 4 + ((id >> 3) & 3);  // batch; tiles of a batch share an XCD
    int p = id >> 5;                                 // 0..14 tile-pair index
    int it = 0, off = p;
    while (off >= 5 - it) { off -= 5 - it; ++it; }
    const int jt = it + off;
    const bool diagTile = (it == jt);

    const int tid = threadIdx.x;
    const int w = tid >> 6, l = tid & 63;
    const int wy = w >> 2, wx = w & 3;               // 2 row-bands x 4 col-bands
    const int lm = l & 15, quad = l >> 4;

    const unsigned short* gA = xb + ((size_t)bt * D_DIM + it * 128) * M_DIM;
    const unsigned short* gB = xb + ((size_t)bt * D_DIM + jt * 128) * M_DIM;

    // staging: lane writes LDS at tid*16B (fixed by global_load_lds); pick the
    // global source chunk so LDS gets XOR-swizzled (bank-conflict-free reads).
    // Invariant: LDS[row][slot c] holds global chunk c ^ ((row>>1)&3).
    const int r0 = tid >> 2;                         // 0..127: full tile rows
    const int cl = (((tid & 3) ^ ((tid >> 3) & 3)) << 3);
    const size_t aoff = (size_t)r0 * M_DIM + cl;
    const int ldst = tid * 8;                        // shorts; 512*8 = 4096 = 8KB

    auto issue = [&](int k, int ph) {
        unsigned short* sA = smem + ph * 8192;
        unsigned short* sB = sA + 4096;
        const int koff = k * BK;
        gload_lds16(gA + aoff + koff, sA + ldst);
        gload_lds16(gB + aoff + koff, sB + ldst);
    };

    f32x4 acc[4][2];
    const f32x4 zero = {0.f, 0.f, 0.f, 0.f};
    #pragma unroll
    for (int i = 0; i < 4; i++)
        #pragma unroll
        for (int j = 0; j < 2; j++) acc[i][j] = zero;

    const int sw = ((quad ^ ((lm >> 1) & 3)) << 3);  // swizzled chunk offset

    issue(0, 0); issue(1, 1); issue(2, 2);  // 6 loads in flight per lane

    int ph = 0;
    for (int k = 0; k < 32; ++k) {
        // wait only for phase k's 2 loads; keep the rest in flight.
        if (k < 30)       asm volatile("s_waitcnt vmcnt(4)" ::: "memory");
        else if (k == 30) asm volatile("s_waitcnt vmcnt(2)" ::: "memory");
        else              asm volatile("s_waitcnt vmcnt(0)" ::: "memory");
        asm volatile("s_barrier" ::: "memory");
        // prefetch k+3 into phase (ph+3)&3 = buffer last read at iter k-1,
        // which the top-of-loop barrier already protects.
        if (k + 3 < 32) issue(k + 3, (ph + 3) & 3);

        const unsigned short* sA = smem + ph * 8192;
        const unsigned short* sB = sA + 4096;
        bf16x8 af[4], bfr[2];
        #pragma unroll
        for (int mi = 0; mi < 4; mi++)
            af[mi] = *(const bf16x8*)&sA[(wy * 64 + mi * 16 + lm) * BK + sw];
        #pragma unroll
        for (int ni = 0; ni < 2; ni++)
            bfr[ni] = *(const bf16x8*)&sB[(wx * 32 + ni * 16 + lm) * BK + sw];

        #pragma unroll
        for (int mi = 0; mi < 4; mi++)
            #pragma unroll
            for (int ni = 0; ni < 2; ni++)
                acc[mi][ni] = __builtin_amdgcn_mfma_f32_16x16x32_bf16(
                    af[mi], bfr[ni], acc[mi][ni], 0, 0, 0);

        ph = (ph + 1) & 3;
    }

    // stage diag slices in LDS (phase-0 bytes; phase 0 was last read at k=28,
    // every wave is past k=31's barrier, so this area is quiescent)
    float* sd = (float*)smem;
    if (tid < 128)      sd[tid] = diag[(size_t)bt * D_DIM + it * 128 + tid];
    else if (tid < 256) sd[tid] = diag[(size_t)bt * D_DIM + jt * 128 + (tid - 128)];
    __syncthreads();

    const float temp = 7.62939453125e-07f;  // 1/(2*640*1024)
    unsigned short* dbase = dcov + (size_t)bt * D_DIM * D_DIM;
    float* rs = rowsum + (size_t)bt * D_DIM;
    float ts = 0.f;
    float cp[2] = {0.f, 0.f};

    #pragma unroll
    for (int mi = 0; mi < 4; mi++) {
        #pragma unroll
        for (int r = 0; r < 4; r++) {
            const int lrow = wy * 64 + mi * 16 + quad * 4 + r;
            const int grow = it * 128 + lrow;
            const float di = sd[lrow];
            float rp = 0.f;
            #pragma unroll
            for (int ni = 0; ni < 2; ni++) {
                const int lcol = wx * 32 + ni * 16 + lm;
                const int gcol = jt * 128 + lcol;
                const float dj = sd[128 + lcol];
                const float g = acc[mi][ni][r];
                const float v = sqrtf(fmaf(temp, fmaxf(di + dj - 2.f * g, 0.f), 1e-5f));
                dbase[(size_t)grow * D_DIM + gcol] = f2bf(v);
                rp += v;
                cp[ni] += v;
            }
            ts += rp;
            rp += __shfl_down(rp, 8, 16);
            rp += __shfl_down(rp, 4, 16);
            rp += __shfl_down(rp, 2, 16);
            rp += __shfl_down(rp, 1, 16);
            if (lm == 0) atomicAdd(&rs[grow], rp);
        }
    }
    if (!diagTile) {
        // mirrored lower tile (jt,it): its row sums == our column sums
        #pragma unroll
        for (int ni = 0; ni < 2; ni++) {
            float c = cp[ni];
            c += __shfl_down(c, 32);
            c += __shfl_down(c, 16);
            if (l < 16) atomicAdd(&rs[jt * 128 + wx * 32 + ni * 16 + lm], c);
        }
    }
    float bs = block_reduce_512(ts);
    if (tid == 0) atomicAdd(&tot[bt], diagTile ? bs : 2.f * bs);
}

// Kernel 3: double centering + triu gather (bf16 dcov read, fp32 out).
__global__ void output_kernel(const unsigned short* __restrict__ dcov,
                              const float* __restrict__ rowsum,
                              const float* __restrict__ tot,
                              float* __restrict__ out) {
    const int b = blockIdx.x / D_DIM;
    const int i = blockIdx.x - b * D_DIM;
    const float inv_d = 1.f / (float)D_DIM;
    const float rmi = rowsum[(size_t)b * D_DIM + i] * inv_d;
    const float tm = tot[b] * (inv_d * inv_d);
    const unsigned short* drow = dcov + ((size_t)b * D_DIM + i) * D_DIM;
    const float* rs = rowsum + (size_t)b * D_DIM;
    float* orow = out + (size_t)b * OUT_ROW + (size_t)i * D_DIM - (size_t)i * (i - 1) / 2;
    for (int j = i + threadIdx.x; j < D_DIM; j += 256)
        orow[j - i] = bf2f(drow[j]) - rmi - rs[j] * inv_d + tm;
}

extern "C" void kernel_launch(void* const* d_in, const int* in_sizes, int n_in,
                              void* d_out, int out_size, void* d_ws, size_t ws_size,
                              hipStream_t stream) {
    const float* x = (const float*)d_in[0];
    float* out = (float*)d_out;

    char* ws = (char*)d_ws;
    unsigned short* xb = (unsigned short*)ws;                 // 41,943,040 B
    size_t off = 41943040;
    float* diag = (float*)(ws + off);           off += 81920;
    unsigned short* dcov = (unsigned short*)(ws + off); off += 26214400;  // bf16
    float* rowsum = (float*)(ws + off);         off += 81920;
    float* tot = (float*)(ws + off);            off += 256;

    cast_diag_kernel<<<dim3(B_DIM * D_DIM), 256, 0, stream>>>(x, xb, diag, rowsum, tot);
    gemm_dcov_kernel<<<dim3(480), 512, 0, stream>>>(xb, diag, dcov, rowsum, tot);
    output_kernel<<<dim3(B_DIM * D_DIM), 256, 0, stream>>>(dcov, rowsum, tot, out);
}